// Round 10
// baseline (1248.302 us; speedup 1.0000x reference)
//
#include <hip/hip_runtime.h>
#include <float.h>

#define N_ROWS 65536
#define D_IN   128
#define DH     64
#define K_CB   2048

typedef const __attribute__((address_space(1))) void* gas_p;
typedef __attribute__((address_space(3))) void* las_p;
typedef _Float16 f16x8 __attribute__((ext_vector_type(8)));
typedef float    f32x4 __attribute__((ext_vector_type(4)));

// ---------------- K1: project 128 -> 64, emit 2-plane fp16 split -----------
// (R5-proven version, unchanged.) z_ = h + m (11+11 mantissa-bit split); rows
// stored [n][64] with a 16B-chunk XOR swizzle: chunk c at c ^ (n&7).
// blocks 0..4095: z rows (16/block) + zero matching one_hot rows (128 KB NT,
// overlapped with compute); blocks 4096..4223: embedding rows + e2.
__global__ __launch_bounds__(256) void k_project(
    const float* __restrict__ Z, const float* __restrict__ emb,
    const float* __restrict__ W, const float* __restrict__ b,
    _Float16* __restrict__ zpl,   // [2][N_ROWS][64]
    _Float16* __restrict__ epl,   // [2][K_CB][64]
    float* __restrict__ e2,
    float* __restrict__ outOH) {  // non-null => zero one_hot rows here
  __shared__ __align__(16) float Wl[64 * 140];   // stride 140: limits read conflicts
  __shared__ __align__(16) float Zl[16 * 128];
  int tid = threadIdx.x;
  const float* src; _Float16* dst; int n0; bool do_e2; size_t plane;
  if ((int)blockIdx.x < 4096) {
    src = Z;   dst = zpl; n0 = blockIdx.x * 16;          do_e2 = false; plane = (size_t)N_ROWS * 64;
  } else {
    src = emb; dst = epl; n0 = (blockIdx.x - 4096) * 16; do_e2 = true;  plane = (size_t)K_CB * 64;
  }

#pragma unroll
  for (int i = 0; i < 8; ++i) {
    int idx4 = tid + 256 * i;            // 0..2047 float4s
    int j = idx4 >> 5;
    int d4 = (idx4 & 31) * 4;
    *(float4*)&Wl[j * 140 + d4] = *(const float4*)(W + j * 128 + d4);
  }
#pragma unroll
  for (int i = 0; i < 2; ++i) {
    int idx4 = tid + 256 * i;            // 0..511 float4s
    int r = idx4 >> 5;
    int d4 = (idx4 & 31) * 4;
    *(float4*)&Zl[r * 128 + d4] = *(const float4*)(src + (size_t)(n0 + r) * 128 + d4);
  }
  int j = tid & 63, g = tid >> 6;        // j = output dim, g = wave -> 4 rows
  float bj = b[j];
  __syncthreads();

  // one_hot zeroing AFTER the barrier: streams under the FMA loop, drains only
  // at kernel end (no barrier waits on these store acks).
  if (outOH && (int)blockIdx.x < 4096) {
    f32x4 zz4 = (f32x4){0.f, 0.f, 0.f, 0.f};
    f32x4* dz = (f32x4*)(outOH + (size_t)n0 * K_CB);   // 16 rows x 2048 = 8192 float4
#pragma unroll
    for (int i = 0; i < 32; ++i)
      __builtin_nontemporal_store(zz4, dz + tid + 256 * i);
  }

  float acc[4] = {0.f, 0.f, 0.f, 0.f};
  for (int d4 = 0; d4 < 128; d4 += 4) {
    float4 w4 = *(float4*)&Wl[j * 140 + d4];
#pragma unroll
    for (int i = 0; i < 4; ++i) {
      float4 z4 = *(float4*)&Zl[(g * 4 + i) * 128 + d4]; // wave-uniform broadcast
      acc[i] = fmaf(z4.x, w4.x, fmaf(z4.y, w4.y, fmaf(z4.z, w4.z, fmaf(z4.w, w4.w, acc[i]))));
    }
  }
#pragma unroll
  for (int i = 0; i < 4; ++i) {
    int n = n0 + g * 4 + i;
    float v = acc[i] + bj;
    _Float16 h = (_Float16)v;  float rm = v - (float)h;
    _Float16 m = (_Float16)rm;
    int pos = (((j >> 3) ^ (n & 7)) << 3) | (j & 7);   // 16B-chunk swizzle
    size_t base = (size_t)n * 64 + pos;
    dst[base]         = h;
    dst[plane + base] = m;
    if (do_e2) {
      float s = v * v;                   // exact fp32 ||e_||^2
#pragma unroll
      for (int off = 32; off > 0; off >>= 1) s += __shfl_xor(s, off, 64);
      if (j == 0) e2[n] = s;
    }
  }
}

// ---------------- K2: MFMA score + argmin + fused epilogue -----------------
// v4: 128 z-rows/block, 512 blocks (2/CU, all co-resident) + T3/T4 counted
// pipeline: 3-deep tile buffers, stage-2-ahead, per-tile s_waitcnt vmcnt(4)
// (drains exactly L_t; L_{t+1} stays in flight) + raw s_barrier. e2 hoisted
// to registers (full unroll keeps indexing static). NO vmem ops in the loop
// except the 4 gload_lds/wave -> clean vmcnt ledger:
//   top of tile t: outstanding = [L_t?, L_{t+1}(4)] -> vmcnt(4) drains L_t
//   (t=31: only L_31 -> vmcnt(0)). L_{t+2} issued AFTER compute(t): its
//   target buf[(t+2)%3] was last read at t-1, all readers passed the top-of-t
//   barrier -> race-free. Numerics identical to v3.
__global__ __launch_bounds__(256, 2) void k_score(
    const _Float16* __restrict__ zpl,  // [2][N_ROWS][64] swizzled
    const _Float16* __restrict__ epl,  // [2][K_CB][64] swizzled
    const float* __restrict__ e2,      // [2048]
    const float* __restrict__ emb,     // [2048][128]
    float* __restrict__ outQ,
    float* __restrict__ outOH,         // null => fallback (write cidx_g)
    int* __restrict__ cidx_g) {
  __shared__ __align__(16) char U[81920];
  _Float16* Zs = (_Float16*)U;              // [2pl][128][64] 32KB (live all loop)
  // tile buffers: U+32768, U+49152, U+65536 (16KB each)

  int tid = threadIdx.x, lane = tid & 63, wid = tid >> 6;
  int quad = lane >> 4, l16 = lane & 15;
  int row0 = blockIdx.x * 128;

  // e2 -> registers (issued first; drained by the prologue vmcnt(8) since 8
  // newer staging loads follow; compiler's own wait is weaker and free)
  float e2r[32];
#pragma unroll
  for (int t = 0; t < 32; ++t) e2r[t] = e2[t * 64 + wid * 16 + l16];

  // stage Zs (2 planes x 16KB) + tile0 -> buf0 + tile1 -> buf1
  for (int q = wid; q < 32; q += 4) {
    int p = q >> 4, within = (q & 15) * 1024;
    const char* g = (const char*)zpl + (size_t)p * ((size_t)N_ROWS * 128)
                  + (size_t)row0 * 128 + within + lane * 16;
    __builtin_amdgcn_global_load_lds((gas_p)g, (las_p)((char*)Zs + p * 16384 + within), 16, 0, 0);
  }
#pragma unroll
  for (int tt = 0; tt < 2; ++tt)
    for (int q = wid; q < 16; q += 4) {
      int p = q >> 3, within = (q & 7) * 1024;
      const char* g = (const char*)epl + (size_t)p * (K_CB * 128)
                    + (size_t)tt * 8192 + within + lane * 16;
      __builtin_amdgcn_global_load_lds((gas_p)g,
          (las_p)(U + 32768 + tt * 16384 + p * 8192 + within), 16, 0, 0);
    }

  // Zs ready when <=8 newest (t0+t1) outstanding
  asm volatile("s_waitcnt vmcnt(8)" ::: "memory");
  __builtin_amdgcn_sched_barrier(0);
  __builtin_amdgcn_s_barrier();
  __builtin_amdgcn_sched_barrier(0);

  // ---- group-0 A-fragments to registers (plane stride 8192 elems) ----
  f16x8 A[2][4][2];
#pragma unroll
  for (int step = 0; step < 2; ++step)
#pragma unroll
    for (int mt = 0; mt < 4; ++mt) {
      int tr = mt * 16 + l16;
      int cph = (step * 4 + quad) ^ (tr & 7);
      const _Float16* pa = Zs + tr * 64 + cph * 8;
      A[step][mt][0] = *(const f16x8*)pa;          // hi
      A[step][mt][1] = *(const f16x8*)(pa + 8192); // mid
    }

  float best[32]; int bidx[32];
#pragma unroll
  for (int s = 0; s < 32; ++s) { best[s] = FLT_MAX; bidx[s] = 0; }

  // ---- counted-vmcnt pipelined tile loop: 32 tiles x 64 cols ----
#pragma unroll
  for (int t = 0; t < 32; ++t) {
    if (t < 31) { asm volatile("s_waitcnt vmcnt(4)" ::: "memory"); }
    else        { asm volatile("s_waitcnt vmcnt(0)" ::: "memory"); }
    __builtin_amdgcn_sched_barrier(0);
    __builtin_amdgcn_s_barrier();
    __builtin_amdgcn_sched_barrier(0);

    const _Float16* esc = (const _Float16*)(U + 32768 + (t % 3) * 16384);
    f32x4 acc0[4], acc1[4];
#pragma unroll
    for (int mt = 0; mt < 4; ++mt) {
      acc0[mt] = (f32x4){0.f, 0.f, 0.f, 0.f};
      acc1[mt] = (f32x4){0.f, 0.f, 0.f, 0.f};
    }

#pragma unroll
    for (int step = 0; step < 2; ++step) {
      int tc = wid * 16 + l16;
      int cph = (step * 4 + quad) ^ (l16 & 7);
      const _Float16* pb = esc + tc * 64 + cph * 8;
      f16x8 Bh = *(const f16x8*)pb;
      f16x8 Bm = *(const f16x8*)(pb + 4096);
      // group 0: A from registers
#pragma unroll
      for (int mt = 0; mt < 4; ++mt) {
        f32x4 c = acc0[mt];
        c = __builtin_amdgcn_mfma_f32_16x16x32_f16(A[step][mt][1], Bm, c, 0, 0, 0); // mm
        c = __builtin_amdgcn_mfma_f32_16x16x32_f16(A[step][mt][1], Bh, c, 0, 0, 0); // mh
        c = __builtin_amdgcn_mfma_f32_16x16x32_f16(A[step][mt][0], Bm, c, 0, 0, 0); // hm
        c = __builtin_amdgcn_mfma_f32_16x16x32_f16(A[step][mt][0], Bh, c, 0, 0, 0); // hh
        acc0[mt] = c;
      }
      // group 1: A from LDS (rows 64..127; (64+x)&7 == x&7 -> same swizzle)
#pragma unroll
      for (int mt = 0; mt < 4; ++mt) {
        int tr = 64 + mt * 16 + l16;
        int cph1 = (step * 4 + quad) ^ (tr & 7);
        const _Float16* pa = Zs + tr * 64 + cph1 * 8;
        f16x8 Ah = *(const f16x8*)pa;
        f16x8 Am = *(const f16x8*)(pa + 8192);
        f32x4 c = acc1[mt];
        c = __builtin_amdgcn_mfma_f32_16x16x32_f16(Am, Bm, c, 0, 0, 0); // mm
        c = __builtin_amdgcn_mfma_f32_16x16x32_f16(Am, Bh, c, 0, 0, 0); // mh
        c = __builtin_amdgcn_mfma_f32_16x16x32_f16(Ah, Bm, c, 0, 0, 0); // hm
        c = __builtin_amdgcn_mfma_f32_16x16x32_f16(Ah, Bh, c, 0, 0, 0); // hh
        acc1[mt] = c;
      }
    }

    // fold into running argmin (strict < + ascending t => earliest index)
    {
      int col = t * 64 + wid * 16 + l16;
      float ev = e2r[t];
#pragma unroll
      for (int mt = 0; mt < 4; ++mt)
#pragma unroll
        for (int r = 0; r < 4; ++r) {
          float s0 = fmaf(-2.0f, acc0[mt][r], ev);
          int slot = mt * 4 + r;
          if (s0 < best[slot]) { best[slot] = s0; bidx[slot] = col; }
          float s1 = fmaf(-2.0f, acc1[mt][r], ev);
          if (s1 < best[16 + slot]) { best[16 + slot] = s1; bidx[16 + slot] = col; }
        }
    }

    // stage tile t+2 (AFTER compute: its buffer's readers at t-1 all passed
    // the top-of-t barrier)
    if (t < 30) {
      char* esn = U + 32768 + ((t + 2) % 3) * 16384;
      for (int q = wid; q < 16; q += 4) {
        int p = q >> 3, within = (q & 7) * 1024;
        const char* g = (const char*)epl + (size_t)p * (K_CB * 128)
                      + (size_t)(t + 2) * 8192 + within + lane * 16;
        __builtin_amdgcn_global_load_lds((gas_p)g, (las_p)(esn + p * 8192 + within), 16, 0, 0);
      }
    }
  }
  __syncthreads();                     // all waves done (Zs reads incl.)

  // ---- cross-lane reduction: 128 rows x 64 (wave,l16) slots; reuse U ----
  float* redm = (float*)U;                  // [128][64] 32KB
  int*   redi = (int*)(U + 32768);          // [128][64] 32KB
  int*   cidx = (int*)(U + 65536);
#pragma unroll
  for (int grp = 0; grp < 2; ++grp)
#pragma unroll
    for (int mt = 0; mt < 4; ++mt)
#pragma unroll
      for (int r = 0; r < 4; ++r) {
        int row = grp * 64 + mt * 16 + quad * 4 + r;  // C-layout: row = quad*4 + reg
        redm[row * 64 + wid * 16 + l16] = best[grp * 16 + mt * 4 + r];
        redi[row * 64 + wid * 16 + l16] = bidx[grp * 16 + mt * 4 + r];
      }
  __syncthreads();
  if (tid < 128) {
    float m = redm[tid * 64]; int mi = redi[tid * 64];
    for (int s = 1; s < 64; ++s) {
      float v = redm[tid * 64 + s]; int vi = redi[tid * 64 + s];
      if (v < m || (v == m && vi < mi)) { m = v; mi = vi; }
    }
    cidx[tid] = mi;
  }
  __syncthreads();

  if (outOH) {
    // zeros were written by k_project (prior kernel on this stream => visible)
    if (tid < 128) outOH[(size_t)(row0 + tid) * K_CB + cidx[tid]] = 1.0f;
  } else {
    if (tid < 128) cidx_g[row0 + tid] = cidx[tid];
  }

  // quantized gather (emb L2-hot); NT stores keep L2 for epl/zpl
#pragma unroll
  for (int i = 0; i < 16; ++i) {
    int idx = tid + 256 * i;           // 0..4095 float4s (128 rows x 32)
    int r = idx >> 5, c = (idx & 31) * 4;
    f32x4 v = *(const f32x4*)(emb + (size_t)cidx[r] * D_IN + c);
    __builtin_nontemporal_store(v, (f32x4*)(outQ + (size_t)(row0 + r) * D_IN + c));
  }
}

// ---------------- K3: fallback epilogue (zero one_hot + scatter) -----------
__global__ void k_epilogue(const int* __restrict__ cidx_g, float* __restrict__ outOH) {
  int tid  = threadIdx.x;
  int row0 = blockIdx.x * 64;
  float4 zz4 = make_float4(0.f, 0.f, 0.f, 0.f);
  for (int r = 0; r < 64; ++r) {
    float4* dst = (float4*)(outOH + (size_t)(row0 + r) * K_CB);
    dst[tid]       = zz4;
    dst[tid + 256] = zz4;
  }
  __syncthreads();
  if (tid < 64) {
    int r = row0 + tid;
    outOH[(size_t)r * K_CB + cidx_g[r]] = 1.0f;
  }
}

extern "C" void kernel_launch(void* const* d_in, const int* in_sizes, int n_in,
                              void* d_out, int out_size, void* d_ws, size_t ws_size,
                              hipStream_t stream) {
  (void)in_sizes; (void)n_in; (void)out_size;
  const float* Z   = (const float*)d_in[0];
  const float* W   = (const float*)d_in[1];
  const float* b   = (const float*)d_in[2];
  const float* emb = (const float*)d_in[3];
  float* outQ  = (float*)d_out;
  float* outOH = (float*)d_out + (size_t)N_ROWS * D_IN;

  // ws layout (bytes): epl 524288 | e2 8192 | (zpl 16777216  OR  cidx 262144)
  char* wsb = (char*)d_ws;
  _Float16* epl = (_Float16*)wsb;
  float*    e2  = (float*)(wsb + 524288);
  const size_t need_primary = 524288 + 8192 + (size_t)2 * N_ROWS * 64 * 2;

  if (ws_size >= need_primary) {
    _Float16* zpl = (_Float16*)(wsb + 532480);
    k_project<<<4224, 256, 0, stream>>>(Z, emb, W, b, zpl, epl, e2, outOH);
    k_score<<<512, 256, 0, stream>>>(zpl, epl, e2, emb, outQ, outOH, nullptr);
  } else {
    // fallback: z planes live in the (not-yet-needed) one_hot region;
    // k_project must NOT zero it (aliases zpl) -> k_epilogue zeroes later.
    int*      cidx_g = (int*)(wsb + 532480);
    _Float16* zpl    = (_Float16*)outOH;
    k_project<<<4224, 256, 0, stream>>>(Z, emb, W, b, zpl, epl, e2, nullptr);
    k_score<<<512, 256, 0, stream>>>(zpl, epl, e2, emb, outQ, nullptr, cidx_g);
    k_epilogue<<<1024, 256, 0, stream>>>(cidx_g, outOH);
  }
}

// Round 11
// 660.737 us; speedup vs baseline: 1.8893x; 1.8893x over previous
//
#include <hip/hip_runtime.h>
#include <float.h>

#define N_ROWS 65536
#define D_IN   128
#define DH     64
#define K_CB   2048

typedef const __attribute__((address_space(1))) void* gas_p;
typedef __attribute__((address_space(3))) void* las_p;
typedef _Float16 f16x8 __attribute__((ext_vector_type(8)));
typedef float    f32x4 __attribute__((ext_vector_type(4)));

// ---------------- K1: project 128 -> 64, emit 2-plane fp16 split -----------
// (R5-proven version, unchanged.) z_ = h + m (11+11 mantissa-bit split); rows
// stored [n][64] with a 16B-chunk XOR swizzle: chunk c at c ^ (n&7).
// blocks 0..4095: z rows (16/block) + zero matching one_hot rows (128 KB NT,
// overlapped with compute); blocks 4096..4223: embedding rows + e2.
__global__ __launch_bounds__(256) void k_project(
    const float* __restrict__ Z, const float* __restrict__ emb,
    const float* __restrict__ W, const float* __restrict__ b,
    _Float16* __restrict__ zpl,   // [2][N_ROWS][64]
    _Float16* __restrict__ epl,   // [2][K_CB][64]
    float* __restrict__ e2,
    float* __restrict__ outOH) {  // non-null => zero one_hot rows here
  __shared__ __align__(16) float Wl[64 * 140];   // stride 140: limits read conflicts
  __shared__ __align__(16) float Zl[16 * 128];
  int tid = threadIdx.x;
  const float* src; _Float16* dst; int n0; bool do_e2; size_t plane;
  if ((int)blockIdx.x < 4096) {
    src = Z;   dst = zpl; n0 = blockIdx.x * 16;          do_e2 = false; plane = (size_t)N_ROWS * 64;
  } else {
    src = emb; dst = epl; n0 = (blockIdx.x - 4096) * 16; do_e2 = true;  plane = (size_t)K_CB * 64;
  }

#pragma unroll
  for (int i = 0; i < 8; ++i) {
    int idx4 = tid + 256 * i;            // 0..2047 float4s
    int j = idx4 >> 5;
    int d4 = (idx4 & 31) * 4;
    *(float4*)&Wl[j * 140 + d4] = *(const float4*)(W + j * 128 + d4);
  }
#pragma unroll
  for (int i = 0; i < 2; ++i) {
    int idx4 = tid + 256 * i;            // 0..511 float4s
    int r = idx4 >> 5;
    int d4 = (idx4 & 31) * 4;
    *(float4*)&Zl[r * 128 + d4] = *(const float4*)(src + (size_t)(n0 + r) * 128 + d4);
  }
  int j = tid & 63, g = tid >> 6;        // j = output dim, g = wave -> 4 rows
  float bj = b[j];
  __syncthreads();

  // one_hot zeroing AFTER the barrier: streams under the FMA loop, drains only
  // at kernel end (no barrier waits on these store acks).
  if (outOH && (int)blockIdx.x < 4096) {
    f32x4 zz4 = (f32x4){0.f, 0.f, 0.f, 0.f};
    f32x4* dz = (f32x4*)(outOH + (size_t)n0 * K_CB);   // 16 rows x 2048 = 8192 float4
#pragma unroll
    for (int i = 0; i < 32; ++i)
      __builtin_nontemporal_store(zz4, dz + tid + 256 * i);
  }

  float acc[4] = {0.f, 0.f, 0.f, 0.f};
  for (int d4 = 0; d4 < 128; d4 += 4) {
    float4 w4 = *(float4*)&Wl[j * 140 + d4];
#pragma unroll
    for (int i = 0; i < 4; ++i) {
      float4 z4 = *(float4*)&Zl[(g * 4 + i) * 128 + d4]; // wave-uniform broadcast
      acc[i] = fmaf(z4.x, w4.x, fmaf(z4.y, w4.y, fmaf(z4.z, w4.z, fmaf(z4.w, w4.w, acc[i]))));
    }
  }
#pragma unroll
  for (int i = 0; i < 4; ++i) {
    int n = n0 + g * 4 + i;
    float v = acc[i] + bj;
    _Float16 h = (_Float16)v;  float rm = v - (float)h;
    _Float16 m = (_Float16)rm;
    int pos = (((j >> 3) ^ (n & 7)) << 3) | (j & 7);   // 16B-chunk swizzle
    size_t base = (size_t)n * 64 + pos;
    dst[base]         = h;
    dst[plane + base] = m;
    if (do_e2) {
      float s = v * v;                   // exact fp32 ||e_||^2
#pragma unroll
      for (int off = 32; off > 0; off >>= 1) s += __shfl_xor(s, off, 64);
      if (j == 0) e2[n] = s;
    }
  }
}

// ---------------- K2: MFMA score + argmin + fused epilogue -----------------
// v5 = v3 (R9, best) + register-neutral pipeline fixes:
//  * 3-deep tile buffers, ROTATING POINTERS (SGPR; no unroll, no e2r array),
//    counted s_waitcnt vmcnt(4) + raw s_barrier. Ledger: top of t outstanding
//    = [L_t(4), L_{t+1}(4)] -> vmcnt(4) drains exactly L_t. L_{t+2} issued
//    AFTER compute(t): its buffer was last read at t-1 and every wave passed
//    the top-of-t barrier after that read -> race-free. No vmcnt(0) in loop.
//  * reduction scratch stride 65: scan reads redm[tid*65+s] hit bank
//    (tid+s)%32 -> conflict-free (was 64-way, 8.3M conflict cycles).
// Register demand identical to v3 (A 64 + best/bidx 64; acc in AGPRs).
__global__ __launch_bounds__(256, 2) void k_score(
    const _Float16* __restrict__ zpl,  // [2][N_ROWS][64] swizzled
    const _Float16* __restrict__ epl,  // [2][K_CB][64] swizzled
    const float* __restrict__ e2,      // [2048]
    const float* __restrict__ emb,     // [2048][128]
    float* __restrict__ outQ,
    float* __restrict__ outOH,         // null => fallback (write cidx_g)
    int* __restrict__ cidx_g) {
  __shared__ __align__(16) char U[81920];
  _Float16* Zs = (_Float16*)U;              // [2pl][128][64] 32KB (live all loop)
  // tile buffers: U+32768, U+49152, U+65536 (16KB each)

  int tid = threadIdx.x, lane = tid & 63, wid = tid >> 6;
  int quad = lane >> 4, l16 = lane & 15;
  int row0 = blockIdx.x * 128;

  // stage Zs (2 planes x 16KB) + tile0 -> buf0 + tile1 -> buf1
  for (int q = wid; q < 32; q += 4) {
    int p = q >> 4, within = (q & 15) * 1024;
    const char* g = (const char*)zpl + (size_t)p * ((size_t)N_ROWS * 128)
                  + (size_t)row0 * 128 + within + lane * 16;
    __builtin_amdgcn_global_load_lds((gas_p)g, (las_p)((char*)Zs + p * 16384 + within), 16, 0, 0);
  }
#pragma unroll
  for (int tt = 0; tt < 2; ++tt)
    for (int q = wid; q < 16; q += 4) {
      int p = q >> 3, within = (q & 7) * 1024;
      const char* g = (const char*)epl + (size_t)p * (K_CB * 128)
                    + (size_t)tt * 8192 + within + lane * 16;
      __builtin_amdgcn_global_load_lds((gas_p)g,
          (las_p)(U + 32768 + tt * 16384 + p * 8192 + within), 16, 0, 0);
    }

  // Zs ready when the 8 newest (tile0+tile1) may remain outstanding
  asm volatile("s_waitcnt vmcnt(8)" ::: "memory");
  __builtin_amdgcn_sched_barrier(0);
  __builtin_amdgcn_s_barrier();
  __builtin_amdgcn_sched_barrier(0);

  // ---- group-0 A-fragments to registers (plane stride 8192 elems) ----
  f16x8 A[2][4][2];
#pragma unroll
  for (int step = 0; step < 2; ++step)
#pragma unroll
    for (int mt = 0; mt < 4; ++mt) {
      int tr = mt * 16 + l16;
      int cph = (step * 4 + quad) ^ (tr & 7);
      const _Float16* pa = Zs + tr * 64 + cph * 8;
      A[step][mt][0] = *(const f16x8*)pa;          // hi
      A[step][mt][1] = *(const f16x8*)(pa + 8192); // mid
    }

  float best[32]; int bidx[32];
#pragma unroll
  for (int s = 0; s < 32; ++s) { best[s] = FLT_MAX; bidx[s] = 0; }

  // rotating tile-buffer pointers (stay in SGPRs)
  char* bA = U + 32768;   // holds tile t
  char* bB = U + 49152;   // holds tile t+1 (in flight or ready)
  char* bC = U + 65536;   // stage target for tile t+2

  // ---- counted-vmcnt pipelined tile loop: 32 tiles x 64 cols ----
  for (int t = 0; t < 32; ++t) {
    if (t < 31) { asm volatile("s_waitcnt vmcnt(4)" ::: "memory"); }
    else        { asm volatile("s_waitcnt vmcnt(0)" ::: "memory"); }
    __builtin_amdgcn_sched_barrier(0);
    __builtin_amdgcn_s_barrier();
    __builtin_amdgcn_sched_barrier(0);

    const _Float16* esc = (const _Float16*)bA;
    int col = t * 64 + wid * 16 + l16;
    float ev = e2[col];                // L2-hot; waited only at the fold

    f32x4 acc0[4], acc1[4];
#pragma unroll
    for (int mt = 0; mt < 4; ++mt) {
      acc0[mt] = (f32x4){0.f, 0.f, 0.f, 0.f};
      acc1[mt] = (f32x4){0.f, 0.f, 0.f, 0.f};
    }

#pragma unroll
    for (int step = 0; step < 2; ++step) {
      int tc = wid * 16 + l16;
      int cph = (step * 4 + quad) ^ (l16 & 7);
      const _Float16* pb = esc + tc * 64 + cph * 8;
      f16x8 Bh = *(const f16x8*)pb;
      f16x8 Bm = *(const f16x8*)(pb + 4096);
      // group 0: A from registers
#pragma unroll
      for (int mt = 0; mt < 4; ++mt) {
        f32x4 c = acc0[mt];
        c = __builtin_amdgcn_mfma_f32_16x16x32_f16(A[step][mt][1], Bm, c, 0, 0, 0); // mm
        c = __builtin_amdgcn_mfma_f32_16x16x32_f16(A[step][mt][1], Bh, c, 0, 0, 0); // mh
        c = __builtin_amdgcn_mfma_f32_16x16x32_f16(A[step][mt][0], Bm, c, 0, 0, 0); // hm
        c = __builtin_amdgcn_mfma_f32_16x16x32_f16(A[step][mt][0], Bh, c, 0, 0, 0); // hh
        acc0[mt] = c;
      }
      // group 1: A from LDS (rows 64..127; (64+x)&7 == x&7 -> same swizzle)
#pragma unroll
      for (int mt = 0; mt < 4; ++mt) {
        int tr = 64 + mt * 16 + l16;
        int cph1 = (step * 4 + quad) ^ (tr & 7);
        const _Float16* pa = Zs + tr * 64 + cph1 * 8;
        f16x8 Ah = *(const f16x8*)pa;
        f16x8 Am = *(const f16x8*)(pa + 8192);
        f32x4 c = acc1[mt];
        c = __builtin_amdgcn_mfma_f32_16x16x32_f16(Am, Bm, c, 0, 0, 0); // mm
        c = __builtin_amdgcn_mfma_f32_16x16x32_f16(Am, Bh, c, 0, 0, 0); // mh
        c = __builtin_amdgcn_mfma_f32_16x16x32_f16(Ah, Bm, c, 0, 0, 0); // hm
        c = __builtin_amdgcn_mfma_f32_16x16x32_f16(Ah, Bh, c, 0, 0, 0); // hh
        acc1[mt] = c;
      }
    }

    // stage tile t+2 into bC (readers of bC's old contents finished at t-1,
    // all passed the top-of-t barrier)
    if (t < 30) {
      for (int q = wid; q < 16; q += 4) {
        int p = q >> 3, within = (q & 7) * 1024;
        const char* g = (const char*)epl + (size_t)p * (K_CB * 128)
                      + (size_t)(t + 2) * 8192 + within + lane * 16;
        __builtin_amdgcn_global_load_lds((gas_p)g, (las_p)(bC + p * 8192 + within), 16, 0, 0);
      }
    }

    // fold into running argmin (strict < + ascending t => earliest index)
#pragma unroll
    for (int mt = 0; mt < 4; ++mt)
#pragma unroll
      for (int r = 0; r < 4; ++r) {
        float s0 = fmaf(-2.0f, acc0[mt][r], ev);
        int slot = mt * 4 + r;
        if (s0 < best[slot]) { best[slot] = s0; bidx[slot] = col; }
        float s1 = fmaf(-2.0f, acc1[mt][r], ev);
        if (s1 < best[16 + slot]) { best[16 + slot] = s1; bidx[16 + slot] = col; }
      }

    char* tmp = bA; bA = bB; bB = bC; bC = tmp;   // rotate
  }
  __syncthreads();                     // all waves done (Zs reads incl.)

  // ---- cross-lane reduction: 128 rows x 64 slots, stride 65 (bank-clean) --
  float* redm = (float*)U;                  // [128][65] 33280 B
  int*   redi = (int*)(U + 33280);          // [128][65] 33280 B
  int*   cidx = (int*)(U + 66560);          // 512 B
#pragma unroll
  for (int grp = 0; grp < 2; ++grp)
#pragma unroll
    for (int mt = 0; mt < 4; ++mt)
#pragma unroll
      for (int r = 0; r < 4; ++r) {
        int row = grp * 64 + mt * 16 + quad * 4 + r;  // C-layout: row = quad*4 + reg
        redm[row * 65 + wid * 16 + l16] = best[grp * 16 + mt * 4 + r];
        redi[row * 65 + wid * 16 + l16] = bidx[grp * 16 + mt * 4 + r];
      }
  __syncthreads();
  if (tid < 128) {
    float m = redm[tid * 65]; int mi = redi[tid * 65];
    for (int s = 1; s < 64; ++s) {
      float v = redm[tid * 65 + s]; int vi = redi[tid * 65 + s];
      if (v < m || (v == m && vi < mi)) { m = v; mi = vi; }
    }
    cidx[tid] = mi;
  }
  __syncthreads();

  if (outOH) {
    // zeros were written by k_project (prior kernel on this stream => visible)
    if (tid < 128) outOH[(size_t)(row0 + tid) * K_CB + cidx[tid]] = 1.0f;
  } else {
    if (tid < 128) cidx_g[row0 + tid] = cidx[tid];
  }

  // quantized gather (emb L2-hot); NT stores keep L2 for epl/zpl
#pragma unroll
  for (int i = 0; i < 16; ++i) {
    int idx = tid + 256 * i;           // 0..4095 float4s (128 rows x 32)
    int r = idx >> 5, c = (idx & 31) * 4;
    f32x4 v = *(const f32x4*)(emb + (size_t)cidx[r] * D_IN + c);
    __builtin_nontemporal_store(v, (f32x4*)(outQ + (size_t)(row0 + r) * D_IN + c));
  }
}

// ---------------- K3: fallback epilogue (zero one_hot + scatter) -----------
__global__ void k_epilogue(const int* __restrict__ cidx_g, float* __restrict__ outOH) {
  int tid  = threadIdx.x;
  int row0 = blockIdx.x * 64;
  float4 zz4 = make_float4(0.f, 0.f, 0.f, 0.f);
  for (int r = 0; r < 64; ++r) {
    float4* dst = (float4*)(outOH + (size_t)(row0 + r) * K_CB);
    dst[tid]       = zz4;
    dst[tid + 256] = zz4;
  }
  __syncthreads();
  if (tid < 64) {
    int r = row0 + tid;
    outOH[(size_t)r * K_CB + cidx_g[r]] = 1.0f;
  }
}

extern "C" void kernel_launch(void* const* d_in, const int* in_sizes, int n_in,
                              void* d_out, int out_size, void* d_ws, size_t ws_size,
                              hipStream_t stream) {
  (void)in_sizes; (void)n_in; (void)out_size;
  const float* Z   = (const float*)d_in[0];
  const float* W   = (const float*)d_in[1];
  const float* b   = (const float*)d_in[2];
  const float* emb = (const float*)d_in[3];
  float* outQ  = (float*)d_out;
  float* outOH = (float*)d_out + (size_t)N_ROWS * D_IN;

  // ws layout (bytes): epl 524288 | e2 8192 | (zpl 16777216  OR  cidx 262144)
  char* wsb = (char*)d_ws;
  _Float16* epl = (_Float16*)wsb;
  float*    e2  = (float*)(wsb + 524288);
  const size_t need_primary = 524288 + 8192 + (size_t)2 * N_ROWS * 64 * 2;

  if (ws_size >= need_primary) {
    _Float16* zpl = (_Float16*)(wsb + 532480);
    k_project<<<4224, 256, 0, stream>>>(Z, emb, W, b, zpl, epl, e2, outOH);
    k_score<<<512, 256, 0, stream>>>(zpl, epl, e2, emb, outQ, outOH, nullptr);
  } else {
    // fallback: z planes live in the (not-yet-needed) one_hot region;
    // k_project must NOT zero it (aliases zpl) -> k_epilogue zeroes later.
    int*      cidx_g = (int*)(wsb + 532480);
    _Float16* zpl    = (_Float16*)outOH;
    k_project<<<4224, 256, 0, stream>>>(Z, emb, W, b, zpl, epl, e2, nullptr);
    k_score<<<512, 256, 0, stream>>>(zpl, epl, e2, emb, outQ, nullptr, cidx_g);
    k_epilogue<<<1024, 256, 0, stream>>>(cidx_g, outOH);
  }
}